// Round 5
// baseline (115.492 us; speedup 1.0000x reference)
//
#include <hip/hip_runtime.h>

// GNN1: drug-relation GNN layer, MI355X (gfx950).
//   b2sum_kernel : b2sum[k] = sum_e b2[k,e]
//   gnn_a        : per-drug 512-thread block: w2sum, W1 hi/lo split,
//                  200x64x64 split-bf16 MFMA GEMM -> S in LDS (XOR swizzle),
//                  coalesced b1-epilogue -> scores[n][k] (+b2sum) to ws.
//                  LDS 51.7KB, 8 waves/block, 3 blocks/CU (24 waves/CU).
//   softgather   : softmax over K, deterministic compaction of nonzero
//                  weights, pipelined ent gather, final linear -> y.
//   bn_kernel    : BatchNorm1d (training stats) over N=846 -> out.

#define NDRUG 846
#define KNB   1024
#define NREL  200
#define BN_EPS 1e-5f

typedef __attribute__((ext_vector_type(8))) short short8;
typedef __attribute__((ext_vector_type(4))) float f32x4;

__device__ __forceinline__ unsigned short f2bf(float x){
    unsigned u = __float_as_uint(x);
    unsigned r = u + 0x7fffu + ((u >> 16) & 1u);
    return (unsigned short)(r >> 16);
}
__device__ __forceinline__ float bf2f(unsigned short h){
    return __uint_as_float(((unsigned)h) << 16);
}

__global__ void b2sum_kernel(const float* __restrict__ b2, float* __restrict__ b2s){
    int k = blockIdx.x*256 + threadIdx.x;
    const float4* p = (const float4*)(b2 + (size_t)k*64);
    float s = 0.f;
    #pragma unroll
    for (int i = 0; i < 16; ++i){ float4 v = p[i]; s += v.x+v.y+v.z+v.w; }
    b2s[k] = s;
}

__global__ __launch_bounds__(512,6) void gnn_a(
    const float* __restrict__ drug_table, const float* __restrict__ rela_table,
    const float* __restrict__ W1,         const float* __restrict__ b1,
    const float* __restrict__ W2,         const int* __restrict__ drug_name,
    const int* __restrict__ adj_rel,      const float* __restrict__ b2s,
    float* __restrict__ scores_g)
{
    __shared__ __align__(16) float sS[12800];   // S[200][64] XOR-swizzled
    __shared__ __align__(16) float w2s[64];
    __shared__ float drug[64];
    unsigned short* Bh = (unsigned short*)sS;          // overlaid: dead after hoist
    unsigned short* Bl = (unsigned short*)(sS + 2048);

    const int t = threadIdx.x;
    const int lane = t & 63;
    const int w = t >> 6;                  // 8 waves
    const int lg = lane >> 4;
    const int l15 = lane & 15;
    const int n = blockIdx.x;

    if (t < 64) drug[t] = drug_table[(size_t)drug_name[n]*64 + t];

    { // w2s[d] = sum_e W2[n,d,e]; 8 lanes per d
        int d = t >> 3, q8 = t & 7;
        const f32x4* W2v = (const f32x4*)(W2 + (size_t)n*4096 + d*64 + q8*8);
        float s = 0.f;
        #pragma unroll
        for (int i = 0; i < 2; ++i){ f32x4 v = W2v[i]; s += v[0]+v[1]+v[2]+v[3]; }
        s += __shfl_xor(s, 1);
        s += __shfl_xor(s, 2);
        s += __shfl_xor(s, 4);
        if (q8 == 0) w2s[d] = s;
    }

    { // stage W1 -> hi/lo bf16, fragment-linear for mfma_16x16x32 B-frags
        const float* W1n = W1 + (size_t)n*4096;
        #pragma unroll
        for (int p = 0; p < 8; ++p){
            int idx = p*512 + t;            // coalesced: d = idx>>6, e = idx&63
            float v = W1n[idx];
            int d = idx >> 6, e = idx & 63;
            int ss = d >> 5, j = d & 7, lgb = (d >> 3) & 3;
            int ln = (lgb << 4) | (e & 15);
            int dst = (((ss<<2) | (e>>4))*64 + ln)*8 + j;
            unsigned short h = f2bf(v);
            Bh[dst] = h;
            Bl[dst] = f2bf(v - bf2f(h));
        }
    }
    __syncthreads();

    float dreg[2][8];
    #pragma unroll
    for (int ss = 0; ss < 2; ++ss)
        #pragma unroll
        for (int j = 0; j < 8; ++j)
            dreg[ss][j] = drug[ss*32 + (lg<<3) + j];

    // hoist all 16 B-fragments (hi+lo) to registers
    short8 bhr[8], blr[8];
    #pragma unroll
    for (int f = 0; f < 8; ++f){
        bhr[f] = *(const short8*)&Bh[(f*64 + lane)*8];
        blr[f] = *(const short8*)&Bl[(f*64 + lane)*8];
    }
    __syncthreads();   // Bh/Bl dead; sS may now be overwritten

    float4 ra[4], rn[4];
    #define LOADT(mi_, dst) do {                                           \
        int mt_ = w + 8*(mi_);                                             \
        if (mt_ < 13){                                                     \
            int r_ = mt_*16 + l15; if (r_ > 199) r_ = 199;                 \
            const float* rp_ = rela_table + (size_t)r_*64 + (lg<<3);       \
            dst[0] = *(const float4*)rp_;       dst[1] = *(const float4*)(rp_+4);  \
            dst[2] = *(const float4*)(rp_+32);  dst[3] = *(const float4*)(rp_+36); \
        }                                                                  \
    } while(0)

    #define CVT2(va, vb, ss_, AH, AL) do {                                 \
        float xs_[8] = {(va).x,(va).y,(va).z,(va).w,(vb).x,(vb).y,(vb).z,(vb).w}; \
        _Pragma("unroll")                                                  \
        for (int j_ = 0; j_ < 8; ++j_){                                    \
            float x_ = xs_[j_] * dreg[ss_][j_];                            \
            unsigned short h_ = f2bf(x_);                                  \
            (AH)[j_] = (short)h_;                                          \
            (AL)[j_] = (short)f2bf(x_ - bf2f(h_));                         \
        }                                                                  \
    } while(0)

    LOADT(0, ra);

    #pragma unroll 1
    for (int mi = 0; mi < 2; ++mi){
        int mt = w + 8*mi;
        if (mt < 13){
            short8 Ah0, Al0, Ah1, Al1;
            CVT2(ra[0], ra[1], 0, Ah0, Al0);
            CVT2(ra[2], ra[3], 1, Ah1, Al1);
            if (mi < 1) LOADT(1, rn);
            f32x4 acc[4] = {};
            #pragma unroll
            for (int nn = 0; nn < 4; ++nn){
                acc[nn] = __builtin_amdgcn_mfma_f32_16x16x32_bf16(Ah0, bhr[nn],   acc[nn], 0,0,0);
                acc[nn] = __builtin_amdgcn_mfma_f32_16x16x32_bf16(Ah0, blr[nn],   acc[nn], 0,0,0);
                acc[nn] = __builtin_amdgcn_mfma_f32_16x16x32_bf16(Al0, bhr[nn],   acc[nn], 0,0,0);
                acc[nn] = __builtin_amdgcn_mfma_f32_16x16x32_bf16(Ah1, bhr[4+nn], acc[nn], 0,0,0);
                acc[nn] = __builtin_amdgcn_mfma_f32_16x16x32_bf16(Ah1, blr[4+nn], acc[nn], 0,0,0);
                acc[nn] = __builtin_amdgcn_mfma_f32_16x16x32_bf16(Al1, bhr[4+nn], acc[nn], 0,0,0);
            }
            // park: word(r,e) = r*64 + ((e>>2 ^ (r&15))<<2) + (e&3)
            int rb = mt*16 + (lg<<2);
            #pragma unroll
            for (int nn = 0; nn < 4; ++nn){
                int e = (nn<<4) | l15;
                int slot = e >> 2, wrd = e & 3;
                #pragma unroll
                for (int q = 0; q < 4; ++q){
                    int r = rb + q;
                    if (r < 200)
                        sS[r*64 + ((slot ^ (r & 15))<<2) + wrd] = acc[nn][q];
                }
            }
            #pragma unroll
            for (int q = 0; q < 4; ++q){ ra[q] = rn[q]; }
        }
    }
    __syncthreads();

    // epilogue: score[k] = sum_e relu(S[arel[k],e] + b1[k,e]) * w2s[e] + b2s[k]
    // 4 lanes per k (ec covers 16 e's); 8 passes x 128 k's per block.
    const int* arel = adj_rel + (size_t)n*KNB;
    const int ec = lane & 3;
    f32x4 w2r[4];
    #pragma unroll
    for (int j = 0; j < 4; ++j) w2r[j] = *(const f32x4*)&w2s[ec*16 + j*4];

    int rr8[8];   // prefetch all pass indices (independent loads, issued early)
    #pragma unroll
    for (int pass = 0; pass < 8; ++pass)
        rr8[pass] = arel[pass*128 + w*16 + (lane >> 2)];

    #pragma unroll 2
    for (int pass = 0; pass < 8; ++pass){
        int k = pass*128 + w*16 + (lane >> 2);
        int rr = rr8[pass];
        const float* b1p = b1 + (size_t)k*64 + ec*16;
        float sc = 0.f;
        #pragma unroll
        for (int j = 0; j < 4; ++j){
            int slot = ec*4 + j;
            f32x4 s4 = *(const f32x4*)&sS[rr*64 + ((slot ^ (rr & 15))<<2)];
            f32x4 bq = *(const f32x4*)(b1p + 4*j);
            #pragma unroll
            for (int q = 0; q < 4; ++q)
                sc += fmaxf(s4[q] + bq[q], 0.f) * w2r[j][q];
        }
        sc += __shfl_xor(sc, 1);
        sc += __shfl_xor(sc, 2);
        if (ec == 0) scores_g[(size_t)n*KNB + k] = sc + b2s[k];
    }
}

__global__ __launch_bounds__(512,8) void softgather(
    const float* __restrict__ scores_g, const int* __restrict__ adj_tail,
    const float* __restrict__ ent_table, const float* __restrict__ drug_table,
    const int* __restrict__ drug_name,   const float* __restrict__ lin_w,
    const float* __restrict__ lin_b,     float* __restrict__ y_out)
{
    __shared__ float sE[KNB];
    __shared__ int list[KNB];
    __shared__ int segc[17];
    __shared__ float red[512];
    __shared__ float wepart[8][64];
    __shared__ float de[128];

    const int t = threadIdx.x;
    const int lane = t & 63;
    const int w = t >> 6;                 // 8 waves
    const int n = blockIdx.x;

    float dpre = 0.f;
    if (t < 64) dpre = drug_table[(size_t)drug_name[n]*64 + t];

    const float* sg = scores_g + (size_t)n*KNB;
    float sv[2]; float mx = -1e30f;
    #pragma unroll
    for (int i = 0; i < 2; ++i){
        sv[i] = sg[t + (i<<9)];
        mx = fmaxf(mx, sv[i]);
    }
    #pragma unroll
    for (int off = 1; off < 64; off <<= 1) mx = fmaxf(mx, __shfl_xor(mx, off, 64));
    if (lane == 0) red[w] = mx;
    __syncthreads();
    mx = red[0];
    #pragma unroll
    for (int s = 1; s < 8; ++s) mx = fmaxf(mx, red[s]);
    float ei[2]; float ps = 0.f;
    #pragma unroll
    for (int i = 0; i < 2; ++i){
        ei[i] = __expf(sv[i] - mx);
        sE[t + (i<<9)] = ei[i];
        ps += ei[i];
    }
    #pragma unroll
    for (int off = 1; off < 64; off <<= 1) ps += __shfl_xor(ps, off, 64);
    if (lane == 0) red[16 + w] = ps;
    __syncthreads();
    float pst = 0.f;
    #pragma unroll
    for (int s = 0; s < 8; ++s) pst += red[16 + s];
    const float inv = 1.f / pst;

    // deterministic compaction of nonzero-weight k's (ordered by k)
    unsigned long long bal[2]; int pos[2];
    #pragma unroll
    for (int i = 0; i < 2; ++i){
        bool nz = (ei[i] != 0.f);
        bal[i] = __ballot(nz);
        pos[i] = (int)__popcll(bal[i] & ((1ull << lane) - 1ull));
        if (lane == 0) segc[i*8 + w] = (int)__popcll(bal[i]);
    }
    __syncthreads();
    if (t == 0){
        int acc = 0;
        #pragma unroll
        for (int s = 0; s < 16; ++s){ int c = segc[s]; segc[s] = acc; acc += c; }
        segc[16] = acc;
    }
    __syncthreads();
    #pragma unroll
    for (int i = 0; i < 2; ++i){
        if (ei[i] != 0.f)
            list[segc[i*8 + w] + pos[i]] = (i<<9) + (w<<6) + lane;
    }
    const int C = segc[16];
    __syncthreads();

    // pipelined gather over compacted list (wave-strided)
    const int* atail = adj_tail + (size_t)n*KNB;
    float awe = 0.f;
    {
        int j = w;
        float ev0 = 0.f, row0 = 0.f;
        if (j < C){
            int k0 = list[j];
            ev0 = sE[k0];
            row0 = ent_table[(size_t)atail[k0]*64 + lane];
        }
        while (j < C){
            int jn = j + 8;
            float ev1 = 0.f, row1 = 0.f;
            if (jn < C){
                int k1 = list[jn];
                ev1 = sE[k1];
                row1 = ent_table[(size_t)atail[k1]*64 + lane];
            }
            awe += ev0 * row0;
            ev0 = ev1; row0 = row1; j = jn;
        }
    }
    wepart[w][lane] = awe;
    __syncthreads();
    if (t < 64){
        float s = 0.f;
        #pragma unroll
        for (int q = 0; q < 8; ++q) s += wepart[q][t];
        de[t]    = s * inv;
        de[64+t] = dpre;
    }
    __syncthreads();

    // y[j] = relu(lin_b[j] + sum_i de[i]*lin_w[j,i]); wave w covers i in [16w,16w+16)
    float yp = 0.f;
    #pragma unroll
    for (int ii = 0; ii < 16; ++ii){
        int i = w*16 + ii;
        yp += de[i] * lin_w[lane*128 + i];
    }
    red[t] = yp;
    __syncthreads();
    if (t < 64){
        float yv = lin_b[t];
        #pragma unroll
        for (int q = 0; q < 8; ++q) yv += red[q*64 + t];
        y_out[(size_t)n*64 + t] = fmaxf(yv, 0.f);
    }
}

__global__ void bn_kernel(const float* __restrict__ y, const float* __restrict__ bn_w,
                          const float* __restrict__ bn_b, float* __restrict__ out){
    __shared__ float r1[4], r2[4];
    const int j = blockIdx.x;
    const int t = threadIdx.x;
    float s1 = 0.f, s2 = 0.f;
    for (int i = t; i < NDRUG; i += 256){
        float v = y[(size_t)i*64 + j];
        s1 += v; s2 += v*v;
    }
    #pragma unroll
    for (int off = 1; off < 64; off <<= 1){
        s1 += __shfl_xor(s1, off, 64);
        s2 += __shfl_xor(s2, off, 64);
    }
    int w = t >> 6, lane = t & 63;
    if (lane == 0){ r1[w] = s1; r2[w] = s2; }
    __syncthreads();
    s1 = r1[0]+r1[1]+r1[2]+r1[3];
    s2 = r2[0]+r2[1]+r2[2]+r2[3];
    float mean = s1 * (1.f/NDRUG);
    float var  = s2 * (1.f/NDRUG) - mean*mean;   // biased (training-mode) variance
    float sc = rsqrtf(var + BN_EPS) * bn_w[j];
    float sh = bn_b[j] - mean*sc;
    for (int i = t; i < NDRUG; i += 256)
        out[(size_t)i*64 + j] = y[(size_t)i*64 + j]*sc + sh;
}

extern "C" void kernel_launch(void* const* d_in, const int* in_sizes, int n_in,
                              void* d_out, int out_size, void* d_ws, size_t ws_size,
                              hipStream_t stream) {
    const float* drug_table = (const float*)d_in[0];
    const float* rela_table = (const float*)d_in[1];
    const float* ent_table  = (const float*)d_in[2];
    const float* W1    = (const float*)d_in[3];
    const float* b1    = (const float*)d_in[4];
    const float* W2    = (const float*)d_in[5];
    const float* b2    = (const float*)d_in[6];
    const float* lin_w = (const float*)d_in[7];
    const float* lin_b = (const float*)d_in[8];
    const float* bn_w  = (const float*)d_in[9];
    const float* bn_b  = (const float*)d_in[10];
    const int* drug_name = (const int*)d_in[11];
    const int* adj_tail  = (const int*)d_in[12];
    const int* adj_rel   = (const int*)d_in[13];
    float* out = (float*)d_out;

    float* b2s     = (float*)d_ws;                  // [1024]
    float* yb      = b2s + KNB;                     // [846*64]
    float* scoresg = yb + NDRUG*64;                 // [846*1024]

    b2sum_kernel<<<KNB/256, 256, 0, stream>>>(b2, b2s);
    gnn_a<<<NDRUG, 512, 0, stream>>>(drug_table, rela_table, W1, b1, W2,
                                     drug_name, adj_rel, b2s, scoresg);
    softgather<<<NDRUG, 512, 0, stream>>>(scoresg, adj_tail, ent_table, drug_table,
                                          drug_name, lin_w, lin_b, yb);
    bn_kernel<<<64, 256, 0, stream>>>(yb, bn_w, bn_b, out);
}

// Round 7
// 71.236 us; speedup vs baseline: 1.6213x; 1.6213x over previous
//
#include <hip/hip_runtime.h>

// GNN1: drug-relation GNN layer, MI355X (gfx950).
//   prep_kernel  : zero scores ws + b2s[k] = sum_e b2[k,e]
//   gnn_a4       : 4 blocks per drug (e-half x k-half). Each block: half-w2sum
//                  (ROW sums of W2), half-W1 hi/lo split, 200x64x32 split-bf16
//                  MFMA GEMM -> S-half[200][32] in LDS (~26KB -> 6 blocks/CU),
//                  b1-epilogue over its k-half, partial scores atomicAdd'd
//                  (exactly 2 addends per element -> deterministic).
//   softgather   : softmax over K (+b2s), deterministic compaction, pipelined
//                  ent gather, final linear -> y.
//   bn_kernel    : BatchNorm1d (training stats) over N=846 -> out.

#define NDRUG 846
#define KNB   1024
#define NREL  200
#define BN_EPS 1e-5f

typedef __attribute__((ext_vector_type(8))) short short8;
typedef __attribute__((ext_vector_type(4))) float f32x4;

__device__ __forceinline__ unsigned short f2bf(float x){
    unsigned u = __float_as_uint(x);
    unsigned r = u + 0x7fffu + ((u >> 16) & 1u);
    return (unsigned short)(r >> 16);
}
__device__ __forceinline__ float bf2f(unsigned short h){
    return __uint_as_float(((unsigned)h) << 16);
}

// blocks [0,3384): zero scores_g; blocks [3384,3388): b2 row sums
__global__ void prep_kernel(const float* __restrict__ b2, float* __restrict__ b2s,
                            float* __restrict__ scores_g){
    int b = blockIdx.x;
    if (b < (NDRUG*KNB)/256){
        scores_g[(size_t)b*256 + threadIdx.x] = 0.f;
    } else {
        int k = (b - (NDRUG*KNB)/256)*256 + threadIdx.x;
        const float4* p = (const float4*)(b2 + (size_t)k*64);
        float s = 0.f;
        #pragma unroll
        for (int i = 0; i < 16; ++i){ float4 v = p[i]; s += v.x+v.y+v.z+v.w; }
        b2s[k] = s;
    }
}

__global__ __launch_bounds__(256,3) void gnn_a4(
    const float* __restrict__ drug_table, const float* __restrict__ rela_table,
    const float* __restrict__ W1,         const float* __restrict__ b1,
    const float* __restrict__ W2,         const int* __restrict__ drug_name,
    const int* __restrict__ adj_rel,      float* __restrict__ scores_g)
{
    __shared__ __align__(16) float sS[6400];    // S-half[200][32], XOR-swizzled
    __shared__ __align__(16) float w2s[32];
    __shared__ float drug[64];
    unsigned short* Bh = (unsigned short*)sS;          // overlay: dead after hoist
    unsigned short* Bl = (unsigned short*)(sS + 1024); // 4KB each

    const int t = threadIdx.x;
    const int lane = t & 63;
    const int w = t >> 6;
    const int lg = lane >> 4;
    const int l15 = lane & 15;
    const int n = blockIdx.x;
    const int ehalf = blockIdx.y & 1;
    const int khalf = blockIdx.y >> 1;
    const int e_base = ehalf << 5;

    if (t < 64) drug[t] = drug_table[(size_t)drug_name[n]*64 + t];

    { // w2s[eo] = sum_j W2[n, e_base+eo, j]  -- ROW sums; 8 lanes per row
        int eo = t >> 3, q8 = t & 7;
        const float* W2n = W2 + (size_t)n*4096 + (size_t)(e_base + eo)*64 + q8*8;
        float s = 0.f;
        #pragma unroll
        for (int i = 0; i < 8; ++i) s += W2n[i];
        s += __shfl_xor(s, 1);
        s += __shfl_xor(s, 2);
        s += __shfl_xor(s, 4);
        if (q8 == 0) w2s[eo] = s;
    }

    { // stage half-W1 -> hi/lo bf16, fragment-linear (frag-group = ss*2+nn)
        const float* W1n = W1 + (size_t)n*4096;
        #pragma unroll
        for (int p = 0; p < 8; ++p){
            int idx = p*256 + t;               // 2048 elems: d = idx>>5, eo = idx&31
            int d = idx >> 5, eo = idx & 31;
            float v = W1n[d*64 + e_base + eo];
            int ss = d >> 5, j = d & 7, lgb = (d >> 3) & 3, nn = eo >> 4;
            int ln = (lgb << 4) | (eo & 15);
            int dst = (((ss<<1)|nn)*64 + ln)*8 + j;
            unsigned short h = f2bf(v);
            Bh[dst] = h;
            Bl[dst] = f2bf(v - bf2f(h));
        }
    }
    __syncthreads();

    float dreg[2][8];
    #pragma unroll
    for (int ss = 0; ss < 2; ++ss)
        #pragma unroll
        for (int j = 0; j < 8; ++j)
            dreg[ss][j] = drug[ss*32 + (lg<<3) + j];

    // hoist the 4 B-fragment pairs (frag-groups: ss*2+nn)
    short8 bhr[4], blr[4];
    #pragma unroll
    for (int f = 0; f < 4; ++f){
        bhr[f] = *(const short8*)&Bh[(f*64 + lane)*8];
        blr[f] = *(const short8*)&Bl[(f*64 + lane)*8];
    }
    __syncthreads();   // Bh/Bl dead; sS writable

    float4 ra[4], rn[4];
    #define LOADT(mi_, dst) do {                                           \
        int mt_ = w + 4*(mi_);                                             \
        if (mt_ < 13){                                                     \
            int r_ = mt_*16 + l15; if (r_ > 199) r_ = 199;                 \
            const float* rp_ = rela_table + (size_t)r_*64 + (lg<<3);       \
            dst[0] = *(const float4*)rp_;       dst[1] = *(const float4*)(rp_+4);  \
            dst[2] = *(const float4*)(rp_+32);  dst[3] = *(const float4*)(rp_+36); \
        }                                                                  \
    } while(0)

    #define CVT2(va, vb, ss_, AH, AL) do {                                 \
        float xs_[8] = {(va).x,(va).y,(va).z,(va).w,(vb).x,(vb).y,(vb).z,(vb).w}; \
        _Pragma("unroll")                                                  \
        for (int j_ = 0; j_ < 8; ++j_){                                    \
            float x_ = xs_[j_] * dreg[ss_][j_];                            \
            unsigned short h_ = (unsigned short)(__float_as_uint(x_) >> 16); \
            (AH)[j_] = (short)h_;                                          \
            (AL)[j_] = (short)f2bf(x_ - bf2f(h_));                         \
        }                                                                  \
    } while(0)

    LOADT(0, ra);

    #pragma unroll 1
    for (int mi = 0; mi < 4; ++mi){
        int mt = w + 4*mi;
        if (mt < 13){
            short8 Ah0, Al0, Ah1, Al1;
            CVT2(ra[0], ra[1], 0, Ah0, Al0);
            CVT2(ra[2], ra[3], 1, Ah1, Al1);
            if (mi < 3) LOADT(mi+1, rn);
            f32x4 acc[2] = {};
            #pragma unroll
            for (int nn = 0; nn < 2; ++nn){
                acc[nn] = __builtin_amdgcn_mfma_f32_16x16x32_bf16(Ah0, bhr[nn],   acc[nn], 0,0,0);
                acc[nn] = __builtin_amdgcn_mfma_f32_16x16x32_bf16(Ah0, blr[nn],   acc[nn], 0,0,0);
                acc[nn] = __builtin_amdgcn_mfma_f32_16x16x32_bf16(Al0, bhr[nn],   acc[nn], 0,0,0);
                acc[nn] = __builtin_amdgcn_mfma_f32_16x16x32_bf16(Ah1, bhr[2+nn], acc[nn], 0,0,0);
                acc[nn] = __builtin_amdgcn_mfma_f32_16x16x32_bf16(Ah1, blr[2+nn], acc[nn], 0,0,0);
                acc[nn] = __builtin_amdgcn_mfma_f32_16x16x32_bf16(Al1, bhr[2+nn], acc[nn], 0,0,0);
            }
            // park: word(r,eo) = r*32 + ((eo>>2 ^ (r&7))<<2) + (eo&3)
            int rb = mt*16 + (lg<<2);
            #pragma unroll
            for (int nn = 0; nn < 2; ++nn){
                int eo = (nn<<4) | l15;
                int slot = eo >> 2, wrd = eo & 3;
                #pragma unroll
                for (int q = 0; q < 4; ++q){
                    int r = rb + q;
                    if (r < 200)
                        sS[r*32 + ((slot ^ (r & 7))<<2) + wrd] = acc[nn][q];
                }
            }
            #pragma unroll
            for (int q = 0; q < 4; ++q){ ra[q] = rn[q]; }
        }
    }
    __syncthreads();

    // epilogue over this block's k-half: partial score = sum_{e in half}
    // relu(S[arel[k],e] + b1[k,e]) * w2s[e];  4 lanes per k, 8 e's per lane.
    const int* arel = adj_rel + (size_t)n*KNB;
    const int ec = lane & 3;
    f32x4 w2r[2];
    #pragma unroll
    for (int j = 0; j < 2; ++j) w2r[j] = *(const f32x4*)&w2s[ec*8 + j*4];

    int rr8[8];
    #pragma unroll
    for (int pass = 0; pass < 8; ++pass)
        rr8[pass] = arel[khalf*512 + pass*64 + w*16 + (lane >> 2)];

    #pragma unroll 2
    for (int pass = 0; pass < 8; ++pass){
        int k = khalf*512 + pass*64 + w*16 + (lane >> 2);
        int rr = rr8[pass];
        const float* b1p = b1 + (size_t)k*64 + e_base + ec*8;
        float sc = 0.f;
        #pragma unroll
        for (int j = 0; j < 2; ++j){
            int slot = ec*2 + j;
            f32x4 s4 = *(const f32x4*)&sS[rr*32 + ((slot ^ (rr & 7))<<2)];
            f32x4 bq = *(const f32x4*)(b1p + 4*j);
            #pragma unroll
            for (int q = 0; q < 4; ++q)
                sc += fmaxf(s4[q] + bq[q], 0.f) * w2r[j][q];
        }
        sc += __shfl_xor(sc, 1);
        sc += __shfl_xor(sc, 2);
        if (ec == 0)
            atomicAdd(&scores_g[(size_t)n*KNB + k], sc);  // 2 addends: deterministic
    }
}

__global__ __launch_bounds__(256,6) void softgather(
    const float* __restrict__ scores_g, const float* __restrict__ b2s,
    const int* __restrict__ adj_tail,   const float* __restrict__ ent_table,
    const float* __restrict__ drug_table, const int* __restrict__ drug_name,
    const float* __restrict__ lin_w,    const float* __restrict__ lin_b,
    float* __restrict__ y_out)
{
    __shared__ float sE[KNB];
    __shared__ int list[KNB];
    __shared__ int segc[17];
    __shared__ float red[256];
    __shared__ float wepart[4][64];
    __shared__ float de[128];

    const int t = threadIdx.x;
    const int lane = t & 63;
    const int w = t >> 6;
    const int n = blockIdx.x;

    float dpre = 0.f;
    if (t < 64) dpre = drug_table[(size_t)drug_name[n]*64 + t];

    const float* sg = scores_g + (size_t)n*KNB;
    float sv[4]; float mx = -1e30f;
    #pragma unroll
    for (int i = 0; i < 4; ++i){
        sv[i] = sg[t + (i<<8)] + b2s[t + (i<<8)];
        mx = fmaxf(mx, sv[i]);
    }
    #pragma unroll
    for (int off = 1; off < 64; off <<= 1) mx = fmaxf(mx, __shfl_xor(mx, off, 64));
    if (lane == 0) red[w] = mx;
    __syncthreads();
    mx = fmaxf(fmaxf(red[0], red[1]), fmaxf(red[2], red[3]));
    float ei[4]; float ps = 0.f;
    #pragma unroll
    for (int i = 0; i < 4; ++i){
        ei[i] = __expf(sv[i] - mx);
        sE[t + (i<<8)] = ei[i];
        ps += ei[i];
    }
    #pragma unroll
    for (int off = 1; off < 64; off <<= 1) ps += __shfl_xor(ps, off, 64);
    if (lane == 0) red[8 + w] = ps;
    __syncthreads();
    const float inv = 1.f / (red[8]+red[9]+red[10]+red[11]);

    // deterministic compaction of nonzero-weight k's (ordered by k)
    unsigned long long bal[4]; int pos[4];
    #pragma unroll
    for (int i = 0; i < 4; ++i){
        bool nz = (ei[i] != 0.f);
        bal[i] = __ballot(nz);
        pos[i] = (int)__popcll(bal[i] & ((1ull << lane) - 1ull));
        if (lane == 0) segc[i*4 + w] = (int)__popcll(bal[i]);
    }
    __syncthreads();
    if (t == 0){
        int acc = 0;
        #pragma unroll
        for (int s = 0; s < 16; ++s){ int c = segc[s]; segc[s] = acc; acc += c; }
        segc[16] = acc;
    }
    __syncthreads();
    #pragma unroll
    for (int i = 0; i < 4; ++i){
        if (ei[i] != 0.f)
            list[segc[i*4 + w] + pos[i]] = (i<<8) + (w<<6) + lane;
    }
    const int C = segc[16];
    __syncthreads();

    // pipelined gather over compacted list (wave-strided)
    const int* atail = adj_tail + (size_t)n*KNB;
    float awe = 0.f;
    {
        int j = w;
        float ev0 = 0.f, row0 = 0.f;
        if (j < C){
            int k0 = list[j];
            ev0 = sE[k0];
            row0 = ent_table[(size_t)atail[k0]*64 + lane];
        }
        while (j < C){
            int jn = j + 4;
            float ev1 = 0.f, row1 = 0.f;
            if (jn < C){
                int k1 = list[jn];
                ev1 = sE[k1];
                row1 = ent_table[(size_t)atail[k1]*64 + lane];
            }
            awe += ev0 * row0;
            ev0 = ev1; row0 = row1; j = jn;
        }
    }
    wepart[w][lane] = awe;
    __syncthreads();
    if (t < 64){
        de[t]    = (wepart[0][t]+wepart[1][t]+wepart[2][t]+wepart[3][t]) * inv;
        de[64+t] = dpre;
    }
    __syncthreads();

    float yp = 0.f;
    #pragma unroll
    for (int ii = 0; ii < 32; ++ii){
        int i = w*32 + ii;
        yp += de[i] * lin_w[lane*128 + i];
    }
    red[t] = yp;
    __syncthreads();
    if (t < 64){
        float yv = lin_b[t] + red[t] + red[64+t] + red[128+t] + red[192+t];
        y_out[(size_t)n*64 + t] = fmaxf(yv, 0.f);
    }
}

__global__ void bn_kernel(const float* __restrict__ y, const float* __restrict__ bn_w,
                          const float* __restrict__ bn_b, float* __restrict__ out){
    __shared__ float r1[4], r2[4];
    const int j = blockIdx.x;
    const int t = threadIdx.x;
    float s1 = 0.f, s2 = 0.f;
    for (int i = t; i < NDRUG; i += 256){
        float v = y[(size_t)i*64 + j];
        s1 += v; s2 += v*v;
    }
    #pragma unroll
    for (int off = 1; off < 64; off <<= 1){
        s1 += __shfl_xor(s1, off, 64);
        s2 += __shfl_xor(s2, off, 64);
    }
    int w = t >> 6, lane = t & 63;
    if (lane == 0){ r1[w] = s1; r2[w] = s2; }
    __syncthreads();
    s1 = r1[0]+r1[1]+r1[2]+r1[3];
    s2 = r2[0]+r2[1]+r2[2]+r2[3];
    float mean = s1 * (1.f/NDRUG);
    float var  = s2 * (1.f/NDRUG) - mean*mean;   // biased (training-mode) variance
    float sc = rsqrtf(var + BN_EPS) * bn_w[j];
    float sh = bn_b[j] - mean*sc;
    for (int i = t; i < NDRUG; i += 256)
        out[(size_t)i*64 + j] = y[(size_t)i*64 + j]*sc + sh;
}

extern "C" void kernel_launch(void* const* d_in, const int* in_sizes, int n_in,
                              void* d_out, int out_size, void* d_ws, size_t ws_size,
                              hipStream_t stream) {
    const float* drug_table = (const float*)d_in[0];
    const float* rela_table = (const float*)d_in[1];
    const float* ent_table  = (const float*)d_in[2];
    const float* W1    = (const float*)d_in[3];
    const float* b1    = (const float*)d_in[4];
    const float* W2    = (const float*)d_in[5];
    const float* b2    = (const float*)d_in[6];
    const float* lin_w = (const float*)d_in[7];
    const float* lin_b = (const float*)d_in[8];
    const float* bn_w  = (const float*)d_in[9];
    const float* bn_b  = (const float*)d_in[10];
    const int* drug_name = (const int*)d_in[11];
    const int* adj_tail  = (const int*)d_in[12];
    const int* adj_rel   = (const int*)d_in[13];
    float* out = (float*)d_out;

    float* b2s     = (float*)d_ws;                  // [1024]
    float* yb      = b2s + KNB;                     // [846*64]
    float* scoresg = yb + NDRUG*64;                 // [846*1024]

    prep_kernel<<<(NDRUG*KNB)/256 + KNB/256, 256, 0, stream>>>(b2, b2s, scoresg);
    gnn_a4<<<dim3(NDRUG,4), 256, 0, stream>>>(drug_table, rela_table, W1, b1, W2,
                                              drug_name, adj_rel, scoresg);
    softgather<<<NDRUG, 256, 0, stream>>>(scoresg, b2s, adj_tail, ent_table, drug_table,
                                          drug_name, lin_w, lin_b, yb);
    bn_kernel<<<64, 256, 0, stream>>>(yb, bn_w, bn_b, out);
}